// Round 1
// 1302.330 us; speedup vs baseline: 1.4881x; 1.4881x over previous
//
#include <hip/hip_runtime.h>
#include <cstdint>

#define EPS 1e-5f
#define PADW 258          // W+2
#define PADROWS 33540     // (H+2)*(W+2) = 130*258
#define NPIX 32768        // H*W per batch

typedef __attribute__((ext_vector_type(8))) short bf16x8;
typedef __attribute__((ext_vector_type(4))) float f32x4;

__device__ __forceinline__ ushort f2bf(float f) {
  union { float f; uint32_t u; } v; v.f = f;
  uint32_t r = v.u + 0x7fffu + ((v.u >> 16) & 1u);  // round-to-nearest-even
  return (ushort)(r >> 16);
}
__device__ __forceinline__ float bf2f(ushort h) {
  union { uint32_t u; float f; } v; v.u = ((uint32_t)h) << 16;
  return v.f;
}
__device__ __forceinline__ void gload_lds16(const void* g, void* lds) {
  __builtin_amdgcn_global_load_lds((__attribute__((address_space(1))) void*)g,
                                   (__attribute__((address_space(3))) void*)lds,
                                   16, 0, 0);
}

// ---------------------------------------------------------------------------
// Unified MFMA GEMM (used for the three 1x1 convs) — unchanged.
// ---------------------------------------------------------------------------
template <int BMODE, int OMODE>
__global__ __launch_bounds__(256) void mfma_gemm(
    const ushort* __restrict__ A, const ushort* __restrict__ B,
    const float* __restrict__ bn, void* __restrict__ OutV,
    int M, int K, int pitchB, int ciB, long strideB, int pitchO, long strideO) {
  const int lane = threadIdx.x & 63;
  const int wave = threadIdx.x >> 6;
  const int wm = (wave & 1) * 64;
  const int wn = (wave >> 1) * 64;
  const int m0 = blockIdx.y * 128;
  const int n0 = blockIdx.x * 128;
  const int z  = blockIdx.z;
  B += (size_t)z * strideB;

  const int h = n0 >> 8, w0 = n0 & 255;
  long prowB;
  if (BMODE == 0) prowB = n0;
  else            prowB = (long)(h + 1) * PADW + (w0 + 1);

  __shared__ __align__(16) ushort Asl[4 * 128 * 8];
  __shared__ __align__(16) ushort Bsl[4 * 128 * 8];

  f32x4 acc[4][4];
#pragma unroll
  for (int mt = 0; mt < 4; ++mt)
#pragma unroll
    for (int nt = 0; nt < 4; ++nt) acc[mt][nt] = (f32x4){0.f, 0.f, 0.f, 0.f};

  for (int k0 = 0; k0 < K; k0 += 32) {
#pragma unroll
    for (int i = 0; i < 2; ++i) {
      int s = wave * 2 + i;
      int c = s * 64 + lane;
      int mm = c & 127, ks = c >> 7;
      gload_lds16(A + (size_t)(m0 + mm) * K + (k0 + ks * 8), Asl + s * 512);
    }
    long rowb; int cib;
    if (BMODE == 2) {
      int tap = k0 >> 10;
      int dy = tap / 3 - 1, dx = tap % 3 - 1;
      rowb = prowB + dy * PADW + dx;
      cib  = k0 & 1023;
    } else {
      rowb = prowB;
      cib  = ciB + k0;
    }
#pragma unroll
    for (int i = 0; i < 2; ++i) {
      int s = wave * 2 + i;
      int c = s * 64 + lane;
      int nn = c & 127, ks = c >> 7;
      gload_lds16(B + (size_t)(rowb + nn) * pitchB + cib + ks * 8, Bsl + s * 512);
    }
    __syncthreads();
    bf16x8 af[4], bfr[4];
#pragma unroll
    for (int t = 0; t < 4; ++t) {
      af[t]  = *(const bf16x8*)(Asl + (((lane >> 4) * 128) + wm + t * 16 + (lane & 15)) * 8);
      bfr[t] = *(const bf16x8*)(Bsl + (((lane >> 4) * 128) + wn + t * 16 + (lane & 15)) * 8);
    }
#pragma unroll
    for (int mt = 0; mt < 4; ++mt)
#pragma unroll
      for (int nt = 0; nt < 4; ++nt)
        acc[mt][nt] = __builtin_amdgcn_mfma_f32_16x16x32_bf16(af[mt], bfr[nt], acc[mt][nt], 0, 0, 0);
    __syncthreads();
  }

  const int q4 = lane >> 4, col = lane & 15;
  float scv[16], bov[16];
#pragma unroll
  for (int mt = 0; mt < 4; ++mt)
#pragma unroll
    for (int r = 0; r < 4; ++r) {
      int m = m0 + wm + mt * 16 + q4 * 4 + r;
      float s = bn[m] * rsqrtf(bn[3 * M + m] + EPS);
      scv[mt * 4 + r] = s;
      bov[mt * 4 + r] = bn[M + m] - bn[2 * M + m] * s;
    }
  if (OMODE == 2) {
    float* Outf = (float*)OutV + (size_t)z * strideO;
#pragma unroll
    for (int mt = 0; mt < 4; ++mt)
#pragma unroll
      for (int r = 0; r < 4; ++r) {
        int m = m0 + wm + mt * 16 + q4 * 4 + r;
        float* rowp = Outf + (size_t)m * NPIX + n0 + wn;
#pragma unroll
        for (int nt = 0; nt < 4; ++nt)
          rowp[nt * 16 + col] = fmaxf(acc[mt][nt][r] * scv[mt * 4 + r] + bov[mt * 4 + r], 0.f);
      }
  } else {
    ushort* Outh = (ushort*)OutV + (size_t)z * strideO;
    long prowO = (OMODE == 0) ? (long)n0 : ((long)(h + 1) * PADW + (w0 + 1));
#pragma unroll
    for (int nt = 0; nt < 4; ++nt) {
      long row = prowO + wn + nt * 16 + col;
      ushort* p = Outh + (size_t)row * pitchO + m0 + wm;
#pragma unroll
      for (int mt = 0; mt < 4; ++mt) {
        ushort4 pk;
        pk.x = f2bf(fmaxf(acc[mt][nt][0] * scv[mt * 4 + 0] + bov[mt * 4 + 0], 0.f));
        pk.y = f2bf(fmaxf(acc[mt][nt][1] * scv[mt * 4 + 1] + bov[mt * 4 + 1], 0.f));
        pk.z = f2bf(fmaxf(acc[mt][nt][2] * scv[mt * 4 + 2] + bov[mt * 4 + 2], 0.f));
        pk.w = f2bf(fmaxf(acc[mt][nt][3] * scv[mt * 4 + 3] + bov[mt * 4 + 3], 0.f));
        *(ushort4*)(p + mt * 16 + q4 * 4) = pk;
      }
    }
  }
}

// ---------------------------------------------------------------------------
// Conv3x3 as halo-LDS implicit GEMM, round 4 rewrite:
//   * Weights repacked to [ci_chunk 32][tap 9][co 512][32 ci] so each A-frag
//     load is a dense, fully-coalesced 1KB wave read (lane&15 -> co stride
//     64B, lane>>4 -> octet stride 16B).
//   * Halo LDS layout [row 3][px 130][oct 4][8 ci]: staging lanes read the 4
//     octets of one pixel contiguously (16 lines/instr vs 64), and each
//     B-frag ds_read_b128 is a dense 1KB wave read -> zero bank conflicts.
//   * Double-buffered halo + stage-at-top pipeline: next chunk's
//     global_load_lds issued before compute; single drain at the trailing
//     __syncthreads. LDS = 2*24,960B -> 3 blocks/CU.
// Grid x = n_tile*4 + m_tile so each XCD keeps one m-tile's weights in L2.
// ---------------------------------------------------------------------------
#define PXS  130          // pixels per halo row (128 + 2 halo)
#define ROWC (PXS * 4)    // 520 chunks per row
#define BUFC (3 * ROWC)   // 1560 chunks per buffer (24,960 B)
__global__ __launch_bounds__(256, 3) void conv3x3_mfma(
    const ushort* __restrict__ W2, const ushort* __restrict__ cat,
    const float* __restrict__ bn, float* __restrict__ out) {
  const int tid  = threadIdx.x;
  const int lane = tid & 63;
  const int wave = tid >> 6;
  const int wm = (wave & 1) * 64;
  const int wn = (wave >> 1) * 64;
  const int m0 = (blockIdx.x & 3) * 128;
  const int n0 = (blockIdx.x >> 2) * 128;
  const int z  = blockIdx.z;
  const int h = n0 >> 8, w0 = n0 & 255;
  const long prow0 = (long)(h + 1) * PADW + (w0 + 1);
  const ushort* Bz = cat + (size_t)z * PADROWS * 1024;

  __shared__ __align__(16) ushort halo[2 * BUFC * 8];  // 49,920 B

  f32x4 acc[4][4];
#pragma unroll
  for (int mt = 0; mt < 4; ++mt)
#pragma unroll
    for (int nt = 0; nt < 4; ++nt) acc[mt][nt] = (f32x4){0.f, 0.f, 0.f, 0.f};

  // Per-thread staging source offsets (ushort units, ci-independent).
  // chunk c = (r*130 + p)*4 + o  ->  global pixel (r-1, p-1), octet o.
  long offs[7];
#pragma unroll
  for (int s = 0; s < 7; ++s) {
    int c = s * 256 + tid;
    if (c < BUFC) {
      int o = c & 3;
      int q = c >> 2;
      int p = q % PXS;
      int r = q / PXS;
      offs[s] = ((prow0 + (long)(r - 1) * PADW + (p - 1)) << 10) + o * 8;
    } else {
      offs[s] = -1;
    }
  }

  auto stage = [&](int buf, int ci0n) {
#pragma unroll
    for (int s = 0; s < 7; ++s)
      if (offs[s] >= 0)
        gload_lds16(Bz + offs[s] + ci0n,
                    halo + ((size_t)buf * BUFC + s * 256 + wave * 64) * 8);
  };

  // Per-lane A base inside one (chunk,tap) 512x32 block:
  //   co = m0 + wm + mt*16 + (lane&15), octet = lane>>4.
  const ushort* Alane = W2 + (size_t)(m0 + wm + (lane & 15)) * 32 + (lane >> 4) * 8;
  const int hlane = 4 * (wn + (lane & 15)) + (lane >> 4);

  stage(0, 0);
  __syncthreads();

  for (int it = 0; it < 32; ++it) {
    if (it < 31) stage((it + 1) & 1, (it + 1) * 32);

    const ushort* Ait = Alane + (size_t)it * (9 * 16384);
    const ushort* hb0 = halo + (size_t)(it & 1) * BUFC * 8;
#pragma unroll
    for (int t = 0; t < 9; ++t) {
      bf16x8 af[4];
#pragma unroll
      for (int mt = 0; mt < 4; ++mt)
        af[mt] = *(const bf16x8*)(Ait + (size_t)t * 16384 + mt * 512);
      const int hb = hlane + (t / 3) * ROWC + (t % 3) * 4;
#pragma unroll
      for (int nt = 0; nt < 4; ++nt) {
        bf16x8 bfr = *(const bf16x8*)(hb0 + (size_t)(hb + nt * 64) * 8);
#pragma unroll
        for (int mt = 0; mt < 4; ++mt)
          acc[mt][nt] = __builtin_amdgcn_mfma_f32_16x16x32_bf16(af[mt], bfr, acc[mt][nt], 0, 0, 0);
      }
    }
    __syncthreads();
  }

  // Epilogue: BN + ReLU, fp32 NCHW out.
  const int q4 = lane >> 4, col = lane & 15;
  float* Outf = out + (size_t)z * 512 * NPIX;
#pragma unroll
  for (int mt = 0; mt < 4; ++mt)
#pragma unroll
    for (int r = 0; r < 4; ++r) {
      int m = m0 + wm + mt * 16 + q4 * 4 + r;
      float s  = bn[m] * rsqrtf(bn[3 * 512 + m] + EPS);
      float bo = bn[512 + m] - bn[2 * 512 + m] * s;
      float* rowp = Outf + (size_t)m * NPIX + n0 + wn;
#pragma unroll
      for (int nt = 0; nt < 4; ++nt)
        rowp[nt * 16 + col] = fmaxf(acc[mt][nt][r] * s + bo, 0.f);
    }
}

// ---------------------------------------------------------------------------
// Tiny GEMM for the k/v path (fp32, negligible cost)
// ---------------------------------------------------------------------------
__global__ __launch_bounds__(64) void small_gemm_kernel(
    const float* __restrict__ Wm, const float* __restrict__ X,
    const float* __restrict__ bn, float* __restrict__ Y,
    int CO, int CI, int KC) {
  int co = blockIdx.x, b = blockIdx.y, kc = threadIdx.x;
  if (kc >= KC) return;
  const float* Xb = X + (size_t)b * CI * KC;
  float acc = 0.f;
  for (int c = 0; c < CI; ++c) acc += Wm[(size_t)co * CI + c] * Xb[(size_t)c * KC + kc];
  float s  = bn[co] * rsqrtf(bn[3 * CO + co] + EPS);
  float bs = bn[CO + co] - bn[2 * CO + co] * s;
  Y[((size_t)b * CO + co) * KC + kc] = fmaxf(acc * s + bs, 0.f);
}

// ---------------------------------------------------------------------------
// Attention: qT/ctxT in [pixel][256ch] bf16; k/v fp32 staged in LDS.
// ---------------------------------------------------------------------------
__global__ __launch_bounds__(256) void attention_kernel(
    const ushort* __restrict__ qT, const float* __restrict__ Kp,
    const float* __restrict__ Vp, ushort* __restrict__ ctxT) {
  int b = blockIdx.y;
  int pix = blockIdx.x * 256 + threadIdx.x;
  __shared__ float ks[256][19], vs[256][19];
  for (int idx = threadIdx.x; idx < 256 * 19; idx += 256) {
    int c = idx / 19, kk = idx % 19;
    ks[c][kk] = Kp[((size_t)b * 256 + c) * 19 + kk];
    vs[c][kk] = Vp[((size_t)b * 256 + c) * 19 + kk];
  }
  __syncthreads();

  const ushort* qrow = qT + ((size_t)b * NPIX + pix) * 256;
  float sim[19];
#pragma unroll
  for (int kk = 0; kk < 19; ++kk) sim[kk] = 0.f;
  for (int c0 = 0; c0 < 256; c0 += 8) {
    uint4 raw = *(const uint4*)(qrow + c0);
    float qf[8] = {bf2f((ushort)(raw.x & 0xffff)), bf2f((ushort)(raw.x >> 16)),
                   bf2f((ushort)(raw.y & 0xffff)), bf2f((ushort)(raw.y >> 16)),
                   bf2f((ushort)(raw.z & 0xffff)), bf2f((ushort)(raw.z >> 16)),
                   bf2f((ushort)(raw.w & 0xffff)), bf2f((ushort)(raw.w >> 16))};
#pragma unroll
    for (int j = 0; j < 8; ++j)
#pragma unroll
      for (int kk = 0; kk < 19; ++kk) sim[kk] += qf[j] * ks[c0 + j][kk];
  }
  const float scale = 0.0625f;
  float mx = -1e30f;
#pragma unroll
  for (int kk = 0; kk < 19; ++kk) { sim[kk] *= scale; mx = fmaxf(mx, sim[kk]); }
  float denom = 0.f;
#pragma unroll
  for (int kk = 0; kk < 19; ++kk) { sim[kk] = __expf(sim[kk] - mx); denom += sim[kk]; }
  float inv = 1.f / denom;
#pragma unroll
  for (int kk = 0; kk < 19; ++kk) sim[kk] *= inv;

  ushort* crow = ctxT + ((size_t)b * NPIX + pix) * 256;
  for (int c0 = 0; c0 < 256; c0 += 8) {
    uint32_t o[4];
#pragma unroll
    for (int j = 0; j < 4; ++j) {
      float v0 = 0.f, v1 = 0.f;
#pragma unroll
      for (int kk = 0; kk < 19; ++kk) {
        v0 += sim[kk] * vs[c0 + j * 2][kk];
        v1 += sim[kk] * vs[c0 + j * 2 + 1][kk];
      }
      o[j] = (uint32_t)f2bf(v0) | ((uint32_t)f2bf(v1) << 16);
    }
    *(uint4*)(crow + c0) = make_uint4(o[0], o[1], o[2], o[3]);
  }
}

// ---------------------------------------------------------------------------
// Transpose x (fp32 [b][512][HW]) into cat_pad (bf16 [b][p][1024], ch 512..1023)
// ---------------------------------------------------------------------------
__global__ __launch_bounds__(256) void transpose_x_kernel(
    const float* __restrict__ x, ushort* __restrict__ cat) {
  int b = blockIdx.z, ci0 = blockIdx.y * 64, n0 = blockIdx.x * 64;
  __shared__ float t[64][65];
  const float* xb = x + ((size_t)b * 512 + ci0) * NPIX + n0;
  for (int i = 0; i < 16; ++i) {
    int idx = i * 256 + threadIdx.x;
    int c = idx >> 6, w = idx & 63;
    t[c][w] = xb[(size_t)c * NPIX + w];
  }
  __syncthreads();
  int h = n0 >> 8, w0 = n0 & 255;
  size_t pbase = ((size_t)b * PADROWS + (size_t)(h + 1) * PADW + (w0 + 1)) * 1024 + 512 + ci0;
  for (int i = 0; i < 16; ++i) {
    int idx = i * 256 + threadIdx.x;
    int n = idx >> 6, c = idx & 63;
    cat[pbase + (size_t)n * 1024 + c] = f2bf(t[c][n]);
  }
}

// ---------------------------------------------------------------------------
// Weight conversions
// ---------------------------------------------------------------------------
__global__ void convert_w_kernel(const float* __restrict__ in, ushort* __restrict__ out, int n) {
  int i = blockIdx.x * 256 + threadIdx.x;
  if (i < n) out[i] = f2bf(in[i]);
}
// Repack wbot (co,ci,ky,kx) fp32 -> W2 bf16 [ci_chunk 32][tap 9][co 512][32 ci]
__global__ void repack_conv_w_kernel(const float* __restrict__ wbot, ushort* __restrict__ Wrb) {
  int idx = blockIdx.x * 256 + threadIdx.x;
  if (idx >= 512 * 9216) return;
  int ci_in = idx & 31;
  int r  = idx >> 5;
  int co = r & 511;
  int tt = r >> 9;
  int t = tt % 9, chunk = tt / 9;
  Wrb[idx] = f2bf(wbot[((size_t)co * 1024 + chunk * 32 + ci_in) * 9 + t]);
}

// ---------------------------------------------------------------------------
extern "C" void kernel_launch(void* const* d_in, const int* in_sizes, int n_in,
                              void* d_out, int out_size, void* d_ws, size_t ws_size,
                              hipStream_t stream) {
  const float* x     = (const float*)d_in[0];
  const float* proxy = (const float*)d_in[1];
  const float* wq1   = (const float*)d_in[2];
  const float* bnq1  = (const float*)d_in[3];
  const float* wq2   = (const float*)d_in[4];
  const float* bnq2  = (const float*)d_in[5];
  const float* wk1   = (const float*)d_in[6];
  const float* bnk1  = (const float*)d_in[7];
  const float* wk2   = (const float*)d_in[8];
  const float* bnk2  = (const float*)d_in[9];
  const float* wv    = (const float*)d_in[10];
  const float* bnv   = (const float*)d_in[11];
  const float* wout  = (const float*)d_in[12];
  const float* bnout = (const float*)d_in[13];
  const float* wbot  = (const float*)d_in[14];
  const float* bnbot = (const float*)d_in[15];
  float* out = (float*)d_out;

  const int B = 2, C = 512, CK = 256, KC = 19;
  char* ws = (char*)d_ws;
  const size_t catBytes = (size_t)B * PADROWS * 1024 * 2;  // 137,379,840
  ushort* cat  = (ushort*)ws;
  ushort* bufA = (ushort*)(ws + 137379840);                // q1T, later ctxT (32 MiB)
  ushort* bufB = (ushort*)(ws + 137379840 + 33554432);     // qT (32 MiB)
  ushort* Wrb  = (ushort*)(ws + 204488704);                // 9 MiB
  ushort* wq1b = (ushort*)(ws + 213925888);
  ushort* wq2b = (ushort*)(ws + 214188032);
  ushort* woutb= (ushort*)(ws + 214319104);
  float*  k1   = (float*)(ws + 214581248);
  float*  k2   = k1 + (size_t)B * CK * KC;
  float*  vv   = k2 + (size_t)B * CK * KC;

  hipMemsetAsync(cat, 0, catBytes, stream);

  convert_w_kernel<<<(CK * C + 255) / 256, 256, 0, stream>>>(wq1, wq1b, CK * C);
  convert_w_kernel<<<(CK * CK + 255) / 256, 256, 0, stream>>>(wq2, wq2b, CK * CK);
  convert_w_kernel<<<(C * CK + 255) / 256, 256, 0, stream>>>(wout, woutb, C * CK);
  repack_conv_w_kernel<<<(512 * 9216 + 255) / 256, 256, 0, stream>>>(wbot, Wrb);

  small_gemm_kernel<<<dim3(CK, B), 64, 0, stream>>>(wk1, proxy, bnk1, k1, CK, C, KC);
  small_gemm_kernel<<<dim3(CK, B), 64, 0, stream>>>(wk2, k1, bnk2, k2, CK, CK, KC);
  small_gemm_kernel<<<dim3(CK, B), 64, 0, stream>>>(wv, proxy, bnv, vv, CK, C, KC);

  transpose_x_kernel<<<dim3(NPIX / 64, 8, B), 256, 0, stream>>>(x, cat);

  const long padStride = (long)PADROWS * 1024;
  const long nckStride = (long)NPIX * 256;

  mfma_gemm<1, 0><<<dim3(NPIX / 128, 2, B), 256, 0, stream>>>(
      wq1b, cat, bnq1, bufA, 256, 512, 1024, 512, padStride, 256, nckStride);
  mfma_gemm<0, 0><<<dim3(NPIX / 128, 2, B), 256, 0, stream>>>(
      wq2b, bufA, bnq2, bufB, 256, 256, 256, 0, nckStride, 256, nckStride);

  attention_kernel<<<dim3(NPIX / 256, B), 256, 0, stream>>>(bufB, k2, vv, bufA);

  mfma_gemm<0, 1><<<dim3(NPIX / 128, 4, B), 256, 0, stream>>>(
      woutb, bufA, bnout, cat, 512, 256, 256, 0, nckStride, 1024, padStride);

  // conv3x3: halo-LDS implicit GEMM; grid.x = n_tile*4 + m_tile (XCD swizzle)
  conv3x3_mfma<<<dim3((NPIX / 128) * 4, 1, B), 256, 0, stream>>>(Wrb, cat, bnbot, out);
}

// Round 2
// 1300.225 us; speedup vs baseline: 1.4906x; 1.0016x over previous
//
#include <hip/hip_runtime.h>
#include <cstdint>

#define EPS 1e-5f
#define PADW 258          // W+2
#define PADROWS 33540     // (H+2)*(W+2) = 130*258
#define NPIX 32768        // H*W per batch

typedef __attribute__((ext_vector_type(8))) short bf16x8;
typedef __attribute__((ext_vector_type(4))) float f32x4;

__device__ __forceinline__ ushort f2bf(float f) {
  union { float f; uint32_t u; } v; v.f = f;
  uint32_t r = v.u + 0x7fffu + ((v.u >> 16) & 1u);  // round-to-nearest-even
  return (ushort)(r >> 16);
}
__device__ __forceinline__ float bf2f(ushort h) {
  union { uint32_t u; float f; } v; v.u = ((uint32_t)h) << 16;
  return v.f;
}
__device__ __forceinline__ void gload_lds16(const void* g, void* lds) {
  __builtin_amdgcn_global_load_lds((__attribute__((address_space(1))) void*)g,
                                   (__attribute__((address_space(3))) void*)lds,
                                   16, 0, 0);
}

// ---------------------------------------------------------------------------
// Unified MFMA GEMM (used for the three 1x1 convs) — unchanged.
// ---------------------------------------------------------------------------
template <int BMODE, int OMODE>
__global__ __launch_bounds__(256) void mfma_gemm(
    const ushort* __restrict__ A, const ushort* __restrict__ B,
    const float* __restrict__ bn, void* __restrict__ OutV,
    int M, int K, int pitchB, int ciB, long strideB, int pitchO, long strideO) {
  const int lane = threadIdx.x & 63;
  const int wave = threadIdx.x >> 6;
  const int wm = (wave & 1) * 64;
  const int wn = (wave >> 1) * 64;
  const int m0 = blockIdx.y * 128;
  const int n0 = blockIdx.x * 128;
  const int z  = blockIdx.z;
  B += (size_t)z * strideB;

  const int h = n0 >> 8, w0 = n0 & 255;
  long prowB;
  if (BMODE == 0) prowB = n0;
  else            prowB = (long)(h + 1) * PADW + (w0 + 1);

  __shared__ __align__(16) ushort Asl[4 * 128 * 8];
  __shared__ __align__(16) ushort Bsl[4 * 128 * 8];

  f32x4 acc[4][4];
#pragma unroll
  for (int mt = 0; mt < 4; ++mt)
#pragma unroll
    for (int nt = 0; nt < 4; ++nt) acc[mt][nt] = (f32x4){0.f, 0.f, 0.f, 0.f};

  for (int k0 = 0; k0 < K; k0 += 32) {
#pragma unroll
    for (int i = 0; i < 2; ++i) {
      int s = wave * 2 + i;
      int c = s * 64 + lane;
      int mm = c & 127, ks = c >> 7;
      gload_lds16(A + (size_t)(m0 + mm) * K + (k0 + ks * 8), Asl + s * 512);
    }
    long rowb; int cib;
    if (BMODE == 2) {
      int tap = k0 >> 10;
      int dy = tap / 3 - 1, dx = tap % 3 - 1;
      rowb = prowB + dy * PADW + dx;
      cib  = k0 & 1023;
    } else {
      rowb = prowB;
      cib  = ciB + k0;
    }
#pragma unroll
    for (int i = 0; i < 2; ++i) {
      int s = wave * 2 + i;
      int c = s * 64 + lane;
      int nn = c & 127, ks = c >> 7;
      gload_lds16(B + (size_t)(rowb + nn) * pitchB + cib + ks * 8, Bsl + s * 512);
    }
    __syncthreads();
    bf16x8 af[4], bfr[4];
#pragma unroll
    for (int t = 0; t < 4; ++t) {
      af[t]  = *(const bf16x8*)(Asl + (((lane >> 4) * 128) + wm + t * 16 + (lane & 15)) * 8);
      bfr[t] = *(const bf16x8*)(Bsl + (((lane >> 4) * 128) + wn + t * 16 + (lane & 15)) * 8);
    }
#pragma unroll
    for (int mt = 0; mt < 4; ++mt)
#pragma unroll
      for (int nt = 0; nt < 4; ++nt)
        acc[mt][nt] = __builtin_amdgcn_mfma_f32_16x16x32_bf16(af[mt], bfr[nt], acc[mt][nt], 0, 0, 0);
    __syncthreads();
  }

  const int q4 = lane >> 4, col = lane & 15;
  float scv[16], bov[16];
#pragma unroll
  for (int mt = 0; mt < 4; ++mt)
#pragma unroll
    for (int r = 0; r < 4; ++r) {
      int m = m0 + wm + mt * 16 + q4 * 4 + r;
      float s = bn[m] * rsqrtf(bn[3 * M + m] + EPS);
      scv[mt * 4 + r] = s;
      bov[mt * 4 + r] = bn[M + m] - bn[2 * M + m] * s;
    }
  if (OMODE == 2) {
    float* Outf = (float*)OutV + (size_t)z * strideO;
#pragma unroll
    for (int mt = 0; mt < 4; ++mt)
#pragma unroll
      for (int r = 0; r < 4; ++r) {
        int m = m0 + wm + mt * 16 + q4 * 4 + r;
        float* rowp = Outf + (size_t)m * NPIX + n0 + wn;
#pragma unroll
        for (int nt = 0; nt < 4; ++nt)
          rowp[nt * 16 + col] = fmaxf(acc[mt][nt][r] * scv[mt * 4 + r] + bov[mt * 4 + r], 0.f);
      }
  } else {
    ushort* Outh = (ushort*)OutV + (size_t)z * strideO;
    long prowO = (OMODE == 0) ? (long)n0 : ((long)(h + 1) * PADW + (w0 + 1));
#pragma unroll
    for (int nt = 0; nt < 4; ++nt) {
      long row = prowO + wn + nt * 16 + col;
      ushort* p = Outh + (size_t)row * pitchO + m0 + wm;
#pragma unroll
      for (int mt = 0; mt < 4; ++mt) {
        ushort4 pk;
        pk.x = f2bf(fmaxf(acc[mt][nt][0] * scv[mt * 4 + 0] + bov[mt * 4 + 0], 0.f));
        pk.y = f2bf(fmaxf(acc[mt][nt][1] * scv[mt * 4 + 1] + bov[mt * 4 + 1], 0.f));
        pk.z = f2bf(fmaxf(acc[mt][nt][2] * scv[mt * 4 + 2] + bov[mt * 4 + 2], 0.f));
        pk.w = f2bf(fmaxf(acc[mt][nt][3] * scv[mt * 4 + 3] + bov[mt * 4 + 3], 0.f));
        *(ushort4*)(p + mt * 16 + q4 * 4) = pk;
      }
    }
  }
}

// ---------------------------------------------------------------------------
// Conv3x3 as halo-LDS implicit GEMM, round 5:
//   * Octet XOR-swizzle o_slot = o ^ ((p>>1)&3): 8 consecutive px hit 8
//     distinct bank-starts -> <=2-way aliasing on ds_read_b128 (free).
//     Both-sides: staging source pre-swizzled, LDS linear, read swizzled
//     via precomputed hoff[12] (compile-time-indexed).
//   * A-register ring prefetch depth 3, prologue (taps 0-2) issued BEFORE
//     staging + sched_barrier(0): A-frag vmcnt waits never drain the
//     staging loads (in-order vmcnt retirement made every early-tap MFMA
//     wait on L3-latency staging before).
//   * s_setprio(1) around each tap's MFMA cluster (T5; wave role diversity
//     now exists between stage/prefetch/MFMA phases).
// ---------------------------------------------------------------------------
#define PXS  130          // pixels per halo row (128 + 2 halo)
#define ROWC (PXS * 4)    // 520 chunks per row
#define BUFC (3 * ROWC)   // 1560 chunks per buffer (24,960 B)
__global__ __launch_bounds__(256, 3) void conv3x3_mfma(
    const ushort* __restrict__ W2, const ushort* __restrict__ cat,
    const float* __restrict__ bn, float* __restrict__ out) {
  const int tid  = threadIdx.x;
  const int lane = tid & 63;
  const int wave = tid >> 6;
  const int wm = (wave & 1) * 64;
  const int wn = (wave >> 1) * 64;
  const int m0 = (blockIdx.x & 3) * 128;
  const int n0 = (blockIdx.x >> 2) * 128;
  const int z  = blockIdx.z;
  const int h = n0 >> 8, w0 = n0 & 255;
  const long prow0 = (long)(h + 1) * PADW + (w0 + 1);
  const ushort* Bz = cat + (size_t)z * PADROWS * 1024;

  __shared__ __align__(16) ushort halo[2 * BUFC * 8];  // 49,920 B

  f32x4 acc[4][4];
#pragma unroll
  for (int mt = 0; mt < 4; ++mt)
#pragma unroll
    for (int nt = 0; nt < 4; ++nt) acc[mt][nt] = (f32x4){0.f, 0.f, 0.f, 0.f};

  // Per-thread staging source offsets (ushort units, ci-independent).
  // LDS slot chunk c = (r*130 + p)*4 + o_slot holds GLOBAL octet
  // o_g = o_slot ^ ((p>>1)&3)  (pre-swizzled source, linear LDS dest).
  long offs[7];
#pragma unroll
  for (int s = 0; s < 7; ++s) {
    int c = s * 256 + tid;
    if (c < BUFC) {
      int o_slot = c & 3;
      int q = c >> 2;
      int p = q % PXS;
      int r = q / PXS;
      int o_g = o_slot ^ ((p >> 1) & 3);
      offs[s] = ((prow0 + (long)(r - 1) * PADW + (p - 1)) << 10) + o_g * 8;
    } else {
      offs[s] = -1;
    }
  }

  auto stage = [&](int buf, int ci0n) {
#pragma unroll
    for (int s = 0; s < 7; ++s)
      if (offs[s] >= 0)
        gload_lds16(Bz + offs[s] + ci0n,
                    halo + ((size_t)buf * BUFC + s * 256 + wave * 64) * 8);
  };

  // Per-lane A base inside one (chunk,tap) 512x32 block:
  //   co = m0 + wm + mt*16 + (lane&15), octet = lane>>4.
  const ushort* Alane = W2 + (size_t)(m0 + wm + (lane & 15)) * 32 + (lane >> 4) * 8;

  // Precompute swizzled halo byte offsets for the 12 (nt,dx) read positions.
  const int p0  = wn + (lane & 15);
  const int oct = lane >> 4;
  int hoff[12];
#pragma unroll
  for (int nt = 0; nt < 4; ++nt)
#pragma unroll
    for (int dx = 0; dx < 3; ++dx) {
      int p = p0 + nt * 16 + dx;
      hoff[nt * 3 + dx] = (p * 4 + (oct ^ ((p >> 1) & 3))) * 16;  // bytes
    }

  stage(0, 0);
  __syncthreads();

  for (int it = 0; it < 32; ++it) {
    const ushort* Ait = Alane + (size_t)it * (9 * 16384);

    // Prologue: A-frags for taps 0-2 into the ring, BEFORE staging issue.
    bf16x8 af[3][4];
#pragma unroll
    for (int t = 0; t < 3; ++t)
#pragma unroll
      for (int mt = 0; mt < 4; ++mt)
        af[t][mt] = *(const bf16x8*)(Ait + (size_t)t * 16384 + mt * 512);

    __builtin_amdgcn_sched_barrier(0);
    if (it < 31) stage((it + 1) & 1, (it + 1) * 32);
    __builtin_amdgcn_sched_barrier(0);

    const char* hb0 = (const char*)(halo + (size_t)(it & 1) * BUFC * 8);
#pragma unroll
    for (int t = 0; t < 9; ++t) {
      const int slot = t % 3;
      const int r = t / 3, dx = t % 3;
      bf16x8 bfr[4];
#pragma unroll
      for (int nt = 0; nt < 4; ++nt)
        bfr[nt] = *(const bf16x8*)(hb0 + r * (ROWC * 16) + hoff[nt * 3 + dx]);
      __builtin_amdgcn_s_setprio(1);
#pragma unroll
      for (int nt = 0; nt < 4; ++nt)
#pragma unroll
        for (int mt = 0; mt < 4; ++mt)
          acc[mt][nt] = __builtin_amdgcn_mfma_f32_16x16x32_bf16(af[slot][mt], bfr[nt], acc[mt][nt], 0, 0, 0);
      __builtin_amdgcn_s_setprio(0);
      // Refill ring with tap t+3 (slot just freed; issued well after staging
      // so its wait never blocks on staging, and it lands under 2 taps' MFMA).
      if (t < 6) {
#pragma unroll
        for (int mt = 0; mt < 4; ++mt)
          af[slot][mt] = *(const bf16x8*)(Ait + (size_t)(t + 3) * 16384 + mt * 512);
      }
    }
    __syncthreads();
  }

  // Epilogue: BN + ReLU, fp32 NCHW out.
  const int q4 = lane >> 4, col = lane & 15;
  float* Outf = out + (size_t)z * 512 * NPIX;
#pragma unroll
  for (int mt = 0; mt < 4; ++mt)
#pragma unroll
    for (int r = 0; r < 4; ++r) {
      int m = m0 + wm + mt * 16 + q4 * 4 + r;
      float s  = bn[m] * rsqrtf(bn[3 * 512 + m] + EPS);
      float bo = bn[512 + m] - bn[2 * 512 + m] * s;
      float* rowp = Outf + (size_t)m * NPIX + n0 + wn;
#pragma unroll
      for (int nt = 0; nt < 4; ++nt)
        rowp[nt * 16 + col] = fmaxf(acc[mt][nt][r] * s + bo, 0.f);
    }
}

// ---------------------------------------------------------------------------
// Tiny GEMM for the k/v path (fp32, negligible cost)
// ---------------------------------------------------------------------------
__global__ __launch_bounds__(64) void small_gemm_kernel(
    const float* __restrict__ Wm, const float* __restrict__ X,
    const float* __restrict__ bn, float* __restrict__ Y,
    int CO, int CI, int KC) {
  int co = blockIdx.x, b = blockIdx.y, kc = threadIdx.x;
  if (kc >= KC) return;
  const float* Xb = X + (size_t)b * CI * KC;
  float acc = 0.f;
  for (int c = 0; c < CI; ++c) acc += Wm[(size_t)co * CI + c] * Xb[(size_t)c * KC + kc];
  float s  = bn[co] * rsqrtf(bn[3 * CO + co] + EPS);
  float bs = bn[CO + co] - bn[2 * CO + co] * s;
  Y[((size_t)b * CO + co) * KC + kc] = fmaxf(acc * s + bs, 0.f);
}

// ---------------------------------------------------------------------------
// Attention: qT/ctxT in [pixel][256ch] bf16; k/v fp32 staged in LDS.
// ---------------------------------------------------------------------------
__global__ __launch_bounds__(256) void attention_kernel(
    const ushort* __restrict__ qT, const float* __restrict__ Kp,
    const float* __restrict__ Vp, ushort* __restrict__ ctxT) {
  int b = blockIdx.y;
  int pix = blockIdx.x * 256 + threadIdx.x;
  __shared__ float ks[256][19], vs[256][19];
  for (int idx = threadIdx.x; idx < 256 * 19; idx += 256) {
    int c = idx / 19, kk = idx % 19;
    ks[c][kk] = Kp[((size_t)b * 256 + c) * 19 + kk];
    vs[c][kk] = Vp[((size_t)b * 256 + c) * 19 + kk];
  }
  __syncthreads();

  const ushort* qrow = qT + ((size_t)b * NPIX + pix) * 256;
  float sim[19];
#pragma unroll
  for (int kk = 0; kk < 19; ++kk) sim[kk] = 0.f;
  for (int c0 = 0; c0 < 256; c0 += 8) {
    uint4 raw = *(const uint4*)(qrow + c0);
    float qf[8] = {bf2f((ushort)(raw.x & 0xffff)), bf2f((ushort)(raw.x >> 16)),
                   bf2f((ushort)(raw.y & 0xffff)), bf2f((ushort)(raw.y >> 16)),
                   bf2f((ushort)(raw.z & 0xffff)), bf2f((ushort)(raw.z >> 16)),
                   bf2f((ushort)(raw.w & 0xffff)), bf2f((ushort)(raw.w >> 16))};
#pragma unroll
    for (int j = 0; j < 8; ++j)
#pragma unroll
      for (int kk = 0; kk < 19; ++kk) sim[kk] += qf[j] * ks[c0 + j][kk];
  }
  const float scale = 0.0625f;
  float mx = -1e30f;
#pragma unroll
  for (int kk = 0; kk < 19; ++kk) { sim[kk] *= scale; mx = fmaxf(mx, sim[kk]); }
  float denom = 0.f;
#pragma unroll
  for (int kk = 0; kk < 19; ++kk) { sim[kk] = __expf(sim[kk] - mx); denom += sim[kk]; }
  float inv = 1.f / denom;
#pragma unroll
  for (int kk = 0; kk < 19; ++kk) sim[kk] *= inv;

  ushort* crow = ctxT + ((size_t)b * NPIX + pix) * 256;
  for (int c0 = 0; c0 < 256; c0 += 8) {
    uint32_t o[4];
#pragma unroll
    for (int j = 0; j < 4; ++j) {
      float v0 = 0.f, v1 = 0.f;
#pragma unroll
      for (int kk = 0; kk < 19; ++kk) {
        v0 += sim[kk] * vs[c0 + j * 2][kk];
        v1 += sim[kk] * vs[c0 + j * 2 + 1][kk];
      }
      o[j] = (uint32_t)f2bf(v0) | ((uint32_t)f2bf(v1) << 16);
    }
    *(uint4*)(crow + c0) = make_uint4(o[0], o[1], o[2], o[3]);
  }
}

// ---------------------------------------------------------------------------
// Transpose x (fp32 [b][512][HW]) into cat_pad (bf16 [b][p][1024], ch 512..1023)
// ---------------------------------------------------------------------------
__global__ __launch_bounds__(256) void transpose_x_kernel(
    const float* __restrict__ x, ushort* __restrict__ cat) {
  int b = blockIdx.z, ci0 = blockIdx.y * 64, n0 = blockIdx.x * 64;
  __shared__ float t[64][65];
  const float* xb = x + ((size_t)b * 512 + ci0) * NPIX + n0;
  for (int i = 0; i < 16; ++i) {
    int idx = i * 256 + threadIdx.x;
    int c = idx >> 6, w = idx & 63;
    t[c][w] = xb[(size_t)c * NPIX + w];
  }
  __syncthreads();
  int h = n0 >> 8, w0 = n0 & 255;
  size_t pbase = ((size_t)b * PADROWS + (size_t)(h + 1) * PADW + (w0 + 1)) * 1024 + 512 + ci0;
  for (int i = 0; i < 16; ++i) {
    int idx = i * 256 + threadIdx.x;
    int n = idx >> 6, c = idx & 63;
    cat[pbase + (size_t)n * 1024 + c] = f2bf(t[c][n]);
  }
}

// ---------------------------------------------------------------------------
// Weight conversions
// ---------------------------------------------------------------------------
__global__ void convert_w_kernel(const float* __restrict__ in, ushort* __restrict__ out, int n) {
  int i = blockIdx.x * 256 + threadIdx.x;
  if (i < n) out[i] = f2bf(in[i]);
}
// Repack wbot (co,ci,ky,kx) fp32 -> W2 bf16 [ci_chunk 32][tap 9][co 512][32 ci]
__global__ void repack_conv_w_kernel(const float* __restrict__ wbot, ushort* __restrict__ Wrb) {
  int idx = blockIdx.x * 256 + threadIdx.x;
  if (idx >= 512 * 9216) return;
  int ci_in = idx & 31;
  int r  = idx >> 5;
  int co = r & 511;
  int tt = r >> 9;
  int t = tt % 9, chunk = tt / 9;
  Wrb[idx] = f2bf(wbot[((size_t)co * 1024 + chunk * 32 + ci_in) * 9 + t]);
}

// ---------------------------------------------------------------------------
extern "C" void kernel_launch(void* const* d_in, const int* in_sizes, int n_in,
                              void* d_out, int out_size, void* d_ws, size_t ws_size,
                              hipStream_t stream) {
  const float* x     = (const float*)d_in[0];
  const float* proxy = (const float*)d_in[1];
  const float* wq1   = (const float*)d_in[2];
  const float* bnq1  = (const float*)d_in[3];
  const float* wq2   = (const float*)d_in[4];
  const float* bnq2  = (const float*)d_in[5];
  const float* wk1   = (const float*)d_in[6];
  const float* bnk1  = (const float*)d_in[7];
  const float* wk2   = (const float*)d_in[8];
  const float* bnk2  = (const float*)d_in[9];
  const float* wv    = (const float*)d_in[10];
  const float* bnv   = (const float*)d_in[11];
  const float* wout  = (const float*)d_in[12];
  const float* bnout = (const float*)d_in[13];
  const float* wbot  = (const float*)d_in[14];
  const float* bnbot = (const float*)d_in[15];
  float* out = (float*)d_out;

  const int B = 2, C = 512, CK = 256, KC = 19;
  char* ws = (char*)d_ws;
  const size_t catBytes = (size_t)B * PADROWS * 1024 * 2;  // 137,379,840
  ushort* cat  = (ushort*)ws;
  ushort* bufA = (ushort*)(ws + 137379840);                // q1T, later ctxT (32 MiB)
  ushort* bufB = (ushort*)(ws + 137379840 + 33554432);     // qT (32 MiB)
  ushort* Wrb  = (ushort*)(ws + 204488704);                // 9 MiB
  ushort* wq1b = (ushort*)(ws + 213925888);
  ushort* wq2b = (ushort*)(ws + 214188032);
  ushort* woutb= (ushort*)(ws + 214319104);
  float*  k1   = (float*)(ws + 214581248);
  float*  k2   = k1 + (size_t)B * CK * KC;
  float*  vv   = k2 + (size_t)B * CK * KC;

  hipMemsetAsync(cat, 0, catBytes, stream);

  convert_w_kernel<<<(CK * C + 255) / 256, 256, 0, stream>>>(wq1, wq1b, CK * C);
  convert_w_kernel<<<(CK * CK + 255) / 256, 256, 0, stream>>>(wq2, wq2b, CK * CK);
  convert_w_kernel<<<(C * CK + 255) / 256, 256, 0, stream>>>(wout, woutb, C * CK);
  repack_conv_w_kernel<<<(512 * 9216 + 255) / 256, 256, 0, stream>>>(wbot, Wrb);

  small_gemm_kernel<<<dim3(CK, B), 64, 0, stream>>>(wk1, proxy, bnk1, k1, CK, C, KC);
  small_gemm_kernel<<<dim3(CK, B), 64, 0, stream>>>(wk2, k1, bnk2, k2, CK, CK, KC);
  small_gemm_kernel<<<dim3(CK, B), 64, 0, stream>>>(wv, proxy, bnv, vv, CK, C, KC);

  transpose_x_kernel<<<dim3(NPIX / 64, 8, B), 256, 0, stream>>>(x, cat);

  const long padStride = (long)PADROWS * 1024;
  const long nckStride = (long)NPIX * 256;

  mfma_gemm<1, 0><<<dim3(NPIX / 128, 2, B), 256, 0, stream>>>(
      wq1b, cat, bnq1, bufA, 256, 512, 1024, 512, padStride, 256, nckStride);
  mfma_gemm<0, 0><<<dim3(NPIX / 128, 2, B), 256, 0, stream>>>(
      wq2b, bufA, bnq2, bufB, 256, 256, 256, 0, nckStride, 256, nckStride);

  attention_kernel<<<dim3(NPIX / 256, B), 256, 0, stream>>>(bufB, k2, vv, bufA);

  mfma_gemm<0, 1><<<dim3(NPIX / 128, 4, B), 256, 0, stream>>>(
      woutb, bufA, bnout, cat, 512, 256, 256, 0, nckStride, 1024, padStride);

  // conv3x3: halo-LDS implicit GEMM; grid.x = n_tile*4 + m_tile (XCD swizzle)
  conv3x3_mfma<<<dim3((NPIX / 128) * 4, 1, B), 256, 0, stream>>>(Wrb, cat, bnbot, out);
}